// Round 5
// baseline (2253.702 us; speedup 1.0000x reference)
//
#include <hip/hip_runtime.h>
#include <math.h>

#define T_SEQ 12
// B=1024, NG=32, G=32, E=64, H=128, PP=512, BOT=1024, MLPD=1024

typedef __bf16 bf16x8 __attribute__((ext_vector_type(8)));
typedef float f32x4 __attribute__((ext_vector_type(4)));
typedef unsigned short u16x8 __attribute__((ext_vector_type(8)));

static __device__ __forceinline__ unsigned short bf16bits(float x) {
  return __builtin_bit_cast(unsigned short, (__bf16)x);
}
static __device__ __forceinline__ bf16x8 asbf(u16x8 v) {
  return __builtin_bit_cast(bf16x8, v);
}

// Workspace layout (float offsets)
enum : int {
  OFF_LP    = 0,        // [1024,2]
  OFF_DIN   = 2048,     // [1024,64]
  OFF_C     = 198656,   // [1024,128]
  OFF_HDEC  = 329728,   // [1024,128]
  OFF_WC    = 460800,   // [2,512]
  OFF_BC    = 461824,   // [512]
  OFF_PW    = 462336,   // [1024,512]
  OFF_AA    = 986624,   // [1024,512]
  OFF_WP2T  = 1510912,  // [1024,512] bf16
  OFF_WM1T  = 1773056,  // [1024,1152] bf16
  OFF_HCATB = 2362880,  // [1024,1152] bf16 (h | pool)
  OFF_WM2TB = 2952704,  // [128,1024] bf16
  OFF_MIDB  = 3018240   // [1024,1024] bf16
};                      // end 3542528 floats = 14.2 MB

// XOR swizzle: permute 16B slots within each 128B group by row&7
#define SWZP(byte, row) ((byte) ^ (((row) & 7) << 4))

__global__ __launch_bounds__(256) void k_setup(
    const float* __restrict__ last_pos, const float* __restrict__ lpr,
    const float* __restrict__ dh, const float* __restrict__ dc,
    const float* __restrict__ W_emb, const float* __restrict__ b_emb,
    float* __restrict__ lp, float* __restrict__ din,
    float* __restrict__ h_dec, float* __restrict__ c) {
  int idx = blockIdx.x * 256 + threadIdx.x;  // 0..131071
  if (idx < 2048) lp[idx] = last_pos[idx];
  h_dec[idx] = dh[idx];
  c[idx] = dc[idx];
  if (idx < 65536) {
    int b = idx >> 6, e = idx & 63;
    din[idx] = lpr[b*2] * W_emb[e] + lpr[b*2+1] * W_emb[64+e] + b_emb[e];
  }
}

__global__ __launch_bounds__(256) void k_wc(
    const float* __restrict__ W_sp, const float* __restrict__ b_sp,
    const float* __restrict__ W_pp1, const float* __restrict__ b_pp1,
    float* __restrict__ Wc, float* __restrict__ bc) {
  int n = blockIdx.x * 256 + threadIdx.x;
  if (n >= 512) return;
  float a0 = 0.f, a1 = 0.f, ab = 0.f;
#pragma unroll 8
  for (int k = 0; k < 64; k++) {
    float w = W_pp1[k*512 + n];
    a0 += W_sp[k] * w;
    a1 += W_sp[64+k] * w;
    ab += b_sp[k] * w;
  }
  Wc[n] = a0; Wc[512+n] = a1; bc[n] = ab + b_pp1[n];
}

// Transpose + convert fp32 [R][C] -> bf16 [C][R]
__global__ __launch_bounds__(256) void k_tcvt(
    const float* __restrict__ src, unsigned short* __restrict__ dst,
    int R, int C) {
  __shared__ float t[32][33];
  const int bx = blockIdx.x * 32, by = blockIdx.y * 32;
  const int tx = threadIdx.x & 31, ty = threadIdx.x >> 5;
#pragma unroll
  for (int i = 0; i < 32; i += 8) t[ty+i][tx] = src[(size_t)(by+ty+i)*C + bx+tx];
  __syncthreads();
#pragma unroll
  for (int i = 0; i < 32; i += 8)
    dst[(size_t)(bx+ty+i)*R + by+tx] = bf16bits(t[tx][ty+i]);
}

// Fused LSTM + h2pos + pool-A-prep: 8 batch rows per block, 512 threads.
__global__ __launch_bounds__(512) void k_step1(
    float* __restrict__ din, const float* __restrict__ h_dec,
    float* __restrict__ c, unsigned short* __restrict__ hcatB,
    float* __restrict__ lp, float* __restrict__ pred,
    const float* __restrict__ W_ih, const float* __restrict__ b_ih,
    const float* __restrict__ W_hh, const float* __restrict__ b_hh,
    const float* __restrict__ W_h2p, const float* __restrict__ b_h2p,
    const float* __restrict__ W_emb, const float* __restrict__ b_emb,
    const float* __restrict__ W1b, const float* __restrict__ Wc,
    const float* __restrict__ bc,
    float* __restrict__ PW, float* __restrict__ Aa, int t) {
  const int b0 = blockIdx.x * 8;
  const int tid = threadIdx.x;
  __shared__ float xh[8*192];
  __shared__ float gl[8*512];
  __shared__ float hbuf[8*128];
  __shared__ float relS[16], curS[16];

  for (int i = tid; i < 1536; i += 512) {
    int r = i / 192, k = i - r*192;
    xh[i] = (k < 64) ? din[(b0+r)*64 + k] : h_dec[(b0+r)*128 + k - 64];
  }
  __syncthreads();
  // gates: thread owns gate-col n for 8 rows
  {
    const int n = tid;
    float acc[8];
    float bias = b_ih[n] + b_hh[n];
#pragma unroll
    for (int r = 0; r < 8; r++) acc[r] = bias;
    const float4* wi = (const float4*)(W_ih + n*64);
#pragma unroll 4
    for (int k4 = 0; k4 < 16; k4++) {
      float4 wv = wi[k4];
#pragma unroll
      for (int r = 0; r < 8; r++) {
        const float* x = xh + r*192 + k4*4;
        acc[r] += x[0]*wv.x + x[1]*wv.y + x[2]*wv.z + x[3]*wv.w;
      }
    }
    const float4* wh = (const float4*)(W_hh + n*128);
#pragma unroll 4
    for (int k4 = 0; k4 < 32; k4++) {
      float4 wv = wh[k4];
#pragma unroll
      for (int r = 0; r < 8; r++) {
        const float* x = xh + r*192 + 64 + k4*4;
        acc[r] += x[0]*wv.x + x[1]*wv.y + x[2]*wv.z + x[3]*wv.w;
      }
    }
#pragma unroll
    for (int r = 0; r < 8; r++) gl[r*512 + n] = acc[r];
  }
  __syncthreads();
  // activations
  for (int o = tid; o < 1024; o += 512) {
    int r = o >> 7, hh = o & 127;
    float ig = gl[r*512 + hh],       fg = gl[r*512 + 128 + hh];
    float gg = gl[r*512 + 256 + hh], og = gl[r*512 + 384 + hh];
    ig = 1.f/(1.f+expf(-ig)); fg = 1.f/(1.f+expf(-fg));
    gg = tanhf(gg);           og = 1.f/(1.f+expf(-og));
    int row = b0 + r;
    float c2 = fg * c[row*128 + hh] + ig * gg;
    float h2 = og * tanhf(c2);
    c[row*128 + hh] = c2;
    hbuf[r*128 + hh] = h2;
    hcatB[(size_t)row*1152 + hh] = bf16bits(h2);
  }
  __syncthreads();
  // pos: rel = h @ W_h2p + b
  if (tid < 256) {
    int r = tid >> 5, col = (tid >> 4) & 1, l16 = tid & 15;
    float s = 0.f;
    for (int k = l16; k < 128; k += 16) s += hbuf[r*128 + k] * W_h2p[k*2 + col];
#pragma unroll
    for (int off = 8; off > 0; off >>= 1) s += __shfl_xor(s, off);
    if (l16 == 0) {
      float rel = s + b_h2p[col];
      float old = lp[(b0+r)*2 + col];
      relS[r*2 + col] = rel;
      curS[r*2 + col] = old + rel;
      lp[(b0+r)*2 + col] = old + rel;
      pred[t*2048 + (b0+r)*2 + col] = rel;
    }
  }
  __syncthreads();
  // din for next step
  {
    int r = tid >> 6, e = tid & 63;
    din[(b0+r)*64 + e] = relS[r*2]*W_emb[e] + relS[r*2+1]*W_emb[64+e] + b_emb[e];
  }
  // A-prep: PW = pos@Wc ; Aa = PW + h@W1b + bc
  {
    const int n = tid;
    float acc[8] = {0.f,0.f,0.f,0.f,0.f,0.f,0.f,0.f};
#pragma unroll 4
    for (int k = 0; k < 128; k++) {
      float wv = W1b[k*512 + n];
#pragma unroll
      for (int r = 0; r < 8; r++) acc[r] += hbuf[r*128 + k] * wv;
    }
    float wc0 = Wc[n], wc1 = Wc[512+n], bcv = bc[n];
#pragma unroll
    for (int r = 0; r < 8; r++) {
      float pw = curS[r*2]*wc0 + curS[r*2+1]*wc1;
      PW[(size_t)(b0+r)*512 + n] = pw;
      Aa[(size_t)(b0+r)*512 + n] = acc[r] + pw + bcv;
    }
  }
}

// --- Pool GEMM: A-tile LDS-resident, B streamed global->reg, no main-loop
// barriers. XCD-aware decode: each XCD gets {8 mt} x {4 g} so its L2 working
// set = 4 scenes' Aa/PW (512 KB) + Wp2t (1 MB) -> B stays L2-resident.
__global__ __launch_bounds__(512) void k_pool4(
    const float* __restrict__ Aa, const float* __restrict__ PW,
    const unsigned short* __restrict__ Wp2t, const float* __restrict__ bp2,
    unsigned short* __restrict__ hcatB) {
  const int bid = blockIdx.x;                 // 0..255
  const int mt = (bid >> 3) & 7;              // XCD = bid&7 (round-robin)
  const int g  = (bid & 7) + ((bid >> 6) << 3);
  const int tid = threadIdx.x, lane = tid & 63, w = tid >> 6;
  const int wr = w >> 2, wcol = w & 3;
  const int l15 = lane & 15, lhi = lane >> 4;
  __shared__ __align__(128) char As[131072];  // [128 rows][1024 B] swizzled

  // Build A tile: one wave-instr writes one full row (conflict-free).
  {
    const int ke = lane * 8;  // bf16 elem offset within row
#pragma unroll 4
    for (int rr = 0; rr < 16; rr++) {
      const int r = rr * 8 + w;
      const int j = r & 31, ii = r >> 5;
      const float* aRow = Aa + (size_t)(g*32 + j)*512 + ke;
      const float* pRow = PW + (size_t)(g*32 + mt*4 + ii)*512 + ke;
      float4 a0 = *(const float4*)aRow;
      float4 a1 = *(const float4*)(aRow + 4);
      float4 p0 = *(const float4*)pRow;
      float4 p1 = *(const float4*)(pRow + 4);
      bf16x8 y;
      y[0] = (__bf16)fmaxf(a0.x - p0.x, 0.f);
      y[1] = (__bf16)fmaxf(a0.y - p0.y, 0.f);
      y[2] = (__bf16)fmaxf(a0.z - p0.z, 0.f);
      y[3] = (__bf16)fmaxf(a0.w - p0.w, 0.f);
      y[4] = (__bf16)fmaxf(a1.x - p1.x, 0.f);
      y[5] = (__bf16)fmaxf(a1.y - p1.y, 0.f);
      y[6] = (__bf16)fmaxf(a1.z - p1.z, 0.f);
      y[7] = (__bf16)fmaxf(a1.w - p1.w, 0.f);
      *(bf16x8*)(As + SWZP(r*1024 + lane*16, r)) = y;
    }
  }
  __syncthreads();

  for (int nt = 0; nt < 4; nt++) {
    const int nbase = nt*256 + wcol*64;
    f32x4 acc[4][4] = {};
    u16x8 bcur[8], bnxt[8];
#pragma unroll
    for (int f = 0; f < 8; f++) {  // f = nf*2 + ks
      const int nf = f >> 1, ks = f & 1;
      bcur[f] = *(const u16x8*)(Wp2t + (size_t)(nbase + nf*16 + l15)*512 +
                                ks*32 + lhi*8);
    }
    for (int k0 = 0; k0 < 512; k0 += 64) {
      if (k0 + 64 < 512) {
#pragma unroll
        for (int f = 0; f < 8; f++) {
          const int nf = f >> 1, ks = f & 1;
          bnxt[f] = *(const u16x8*)(Wp2t + (size_t)(nbase + nf*16 + l15)*512 +
                                    k0 + 64 + ks*32 + lhi*8);
        }
      }
#pragma unroll
      for (int ks = 0; ks < 2; ks++) {
        bf16x8 af[4];
#pragma unroll
        for (int mf = 0; mf < 4; mf++) {
          const int row = wr*64 + mf*16 + l15;
          af[mf] = *(const bf16x8*)(As +
              SWZP(row*1024 + (k0 + ks*32 + lhi*8)*2, row));
        }
#pragma unroll
        for (int mf = 0; mf < 4; mf++)
#pragma unroll
          for (int nf = 0; nf < 4; nf++)
            acc[mf][nf] = __builtin_amdgcn_mfma_f32_16x16x32_bf16(
                af[mf], asbf(bcur[nf*2 + ks]), acc[mf][nf], 0, 0, 0);
      }
#pragma unroll
      for (int f = 0; f < 8; f++) bcur[f] = bnxt[f];
    }
    // epilogue: max over j within wave rows, then cross-lane (lhi), bias, relu
#pragma unroll
    for (int isub = 0; isub < 2; isub++)
#pragma unroll
      for (int nf = 0; nf < 4; nf++) {
        f32x4 v0 = acc[isub*2][nf], v1 = acc[isub*2 + 1][nf];
        float mx = fmaxf(fmaxf(fmaxf(v0[0], v0[1]), fmaxf(v0[2], v0[3])),
                         fmaxf(fmaxf(v1[0], v1[1]), fmaxf(v1[2], v1[3])));
        mx = fmaxf(mx, __shfl_xor(mx, 16));
        mx = fmaxf(mx, __shfl_xor(mx, 32));
        if (lane < 16) {
          const int n = nbase + nf*16 + lane;
          const int i = mt*4 + wr*2 + isub;
          hcatB[(size_t)(g*32 + i)*1152 + 128 + n] =
              bf16bits(fmaxf(mx + bp2[n], 0.f));
        }
      }
  }
}

// mid = relu(hcatB @ Wm1t^T + b_m1) -> bf16 midB. Global-direct MFMA.
// Grid (8 nt, 16 mt) = 128 blocks, 8 waves (2m x 4n), wave 32m x 32n,
// K=128 per pipelined iter (9 iters). XCD = nt -> B-slice L2-resident.
__global__ __launch_bounds__(512) void k_m1h(
    const unsigned short* __restrict__ A, const unsigned short* __restrict__ Bw,
    const float* __restrict__ bias, unsigned short* __restrict__ outB) {
  const int nt = blockIdx.x;   // 0..7
  const int mt = blockIdx.y;   // 0..15
  const int tid = threadIdx.x, lane = tid & 63, w = tid >> 6;
  const int wrm = w >> 2, wcn = w & 3;
  const int l15 = lane & 15, lhi = lane >> 4;
  const int m0 = mt*64 + wrm*32, n0 = nt*128 + wcn*32;
  const unsigned short* Abase = A  + (size_t)m0*1152;
  const unsigned short* Bbase = Bw + (size_t)n0*1152;
  f32x4 acc[2][2] = {};
  u16x8 ac[8], bc_[8], an[8], bn[8];  // f = mf*4 + ks
#pragma unroll
  for (int f = 0; f < 8; f++) {
    const int mf = f >> 2, ks = f & 3;
    ac[f]  = *(const u16x8*)(Abase + (size_t)(mf*16 + l15)*1152 + ks*32 + lhi*8);
    bc_[f] = *(const u16x8*)(Bbase + (size_t)(mf*16 + l15)*1152 + ks*32 + lhi*8);
  }
  for (int c = 0; c < 9; c++) {
    if (c < 8) {
      const int kn = (c+1)*128;
#pragma unroll
      for (int f = 0; f < 8; f++) {
        const int mf = f >> 2, ks = f & 3;
        an[f] = *(const u16x8*)(Abase + (size_t)(mf*16 + l15)*1152 + kn + ks*32 + lhi*8);
        bn[f] = *(const u16x8*)(Bbase + (size_t)(mf*16 + l15)*1152 + kn + ks*32 + lhi*8);
      }
    }
#pragma unroll
    for (int ks = 0; ks < 4; ks++)
#pragma unroll
      for (int mf = 0; mf < 2; mf++)
#pragma unroll
        for (int nf = 0; nf < 2; nf++)
          acc[mf][nf] = __builtin_amdgcn_mfma_f32_16x16x32_bf16(
              asbf(ac[mf*4 + ks]), asbf(bc_[nf*4 + ks]), acc[mf][nf], 0, 0, 0);
#pragma unroll
    for (int f = 0; f < 8; f++) { ac[f] = an[f]; bc_[f] = bn[f]; }
  }
#pragma unroll
  for (int mf = 0; mf < 2; mf++)
#pragma unroll
    for (int nf = 0; nf < 2; nf++) {
      const int col = n0 + nf*16 + l15;
      const float bv = bias[col];
#pragma unroll
      for (int r = 0; r < 4; r++) {
        const int row = m0 + mf*16 + lhi*4 + r;
        outB[(size_t)row*1024 + col] = bf16bits(fmaxf(acc[mf][nf][r] + bv, 0.f));
      }
    }
}

// h_dec = relu(midB @ Wm2tB^T + b_m2) fp32. Grid 32 (mt), 4 waves (1m x 4n),
// wave 32m x 32n, K=128 per pipelined iter (8 iters).
__global__ __launch_bounds__(256) void k_m2h(
    const unsigned short* __restrict__ midB,
    const unsigned short* __restrict__ Wm2tB,
    const float* __restrict__ bm2, float* __restrict__ h_dec) {
  const int mt = blockIdx.x;   // 0..31
  const int lane = threadIdx.x & 63, w = threadIdx.x >> 6;
  const int l15 = lane & 15, lhi = lane >> 4;
  const int m0 = mt*32, n0 = w*32;
  const unsigned short* Abase = midB  + (size_t)m0*1024;
  const unsigned short* Bbase = Wm2tB + (size_t)n0*1024;
  f32x4 acc[2][2] = {};
  u16x8 ac[8], bc_[8], an[8], bn[8];
#pragma unroll
  for (int f = 0; f < 8; f++) {
    const int mf = f >> 2, ks = f & 3;
    ac[f]  = *(const u16x8*)(Abase + (size_t)(mf*16 + l15)*1024 + ks*32 + lhi*8);
    bc_[f] = *(const u16x8*)(Bbase + (size_t)(mf*16 + l15)*1024 + ks*32 + lhi*8);
  }
  for (int c = 0; c < 8; c++) {
    if (c < 7) {
      const int kn = (c+1)*128;
#pragma unroll
      for (int f = 0; f < 8; f++) {
        const int mf = f >> 2, ks = f & 3;
        an[f] = *(const u16x8*)(Abase + (size_t)(mf*16 + l15)*1024 + kn + ks*32 + lhi*8);
        bn[f] = *(const u16x8*)(Bbase + (size_t)(mf*16 + l15)*1024 + kn + ks*32 + lhi*8);
      }
    }
#pragma unroll
    for (int ks = 0; ks < 4; ks++)
#pragma unroll
      for (int mf = 0; mf < 2; mf++)
#pragma unroll
        for (int nf = 0; nf < 2; nf++)
          acc[mf][nf] = __builtin_amdgcn_mfma_f32_16x16x32_bf16(
              asbf(ac[mf*4 + ks]), asbf(bc_[nf*4 + ks]), acc[mf][nf], 0, 0, 0);
#pragma unroll
    for (int f = 0; f < 8; f++) { ac[f] = an[f]; bc_[f] = bn[f]; }
  }
#pragma unroll
  for (int mf = 0; mf < 2; mf++)
#pragma unroll
    for (int nf = 0; nf < 2; nf++) {
      const int col = n0 + nf*16 + l15;
      const float bv = bm2[col];
#pragma unroll
      for (int r = 0; r < 4; r++) {
        const int row = m0 + mf*16 + lhi*4 + r;
        h_dec[(size_t)row*128 + col] = fmaxf(acc[mf][nf][r] + bv, 0.f);
      }
    }
}

__global__ __launch_bounds__(256) void k_hfin(const float* __restrict__ h_dec,
                                              float* __restrict__ out) {
  int idx = blockIdx.x * 256 + threadIdx.x;
  if (idx < 131072) out[24576 + idx] = h_dec[idx];
}

extern "C" void kernel_launch(void* const* d_in, const int* in_sizes, int n_in,
                              void* d_out, int out_size, void* d_ws, size_t ws_size,
                              hipStream_t stream) {
  const float* last_pos = (const float*)d_in[0];
  const float* lpr      = (const float*)d_in[1];
  const float* dh       = (const float*)d_in[2];
  const float* dc       = (const float*)d_in[3];
  const float* W_emb = (const float*)d_in[5];
  const float* b_emb = (const float*)d_in[6];
  const float* W_ih  = (const float*)d_in[7];
  const float* b_ih  = (const float*)d_in[8];
  const float* W_hh  = (const float*)d_in[9];
  const float* b_hh  = (const float*)d_in[10];
  const float* W_h2p = (const float*)d_in[11];
  const float* b_h2p = (const float*)d_in[12];
  const float* W_sp  = (const float*)d_in[13];
  const float* b_sp  = (const float*)d_in[14];
  const float* W_pp1 = (const float*)d_in[15];
  const float* b_pp1 = (const float*)d_in[16];
  const float* W_pp2 = (const float*)d_in[17];
  const float* b_pp2 = (const float*)d_in[18];
  const float* W_m1  = (const float*)d_in[19];
  const float* b_m1  = (const float*)d_in[20];
  const float* W_m2  = (const float*)d_in[21];
  const float* b_m2  = (const float*)d_in[22];

  float* ws    = (float*)d_ws;
  float* lp    = ws + OFF_LP;
  float* din   = ws + OFF_DIN;
  float* cst   = ws + OFF_C;
  float* h_dec = ws + OFF_HDEC;
  float* Wc    = ws + OFF_WC;
  float* bc    = ws + OFF_BC;
  float* PW    = ws + OFF_PW;
  float* Aa    = ws + OFF_AA;
  unsigned short* Wp2t  = (unsigned short*)(ws + OFF_WP2T);
  unsigned short* Wm1t  = (unsigned short*)(ws + OFF_WM1T);
  unsigned short* hcatB = (unsigned short*)(ws + OFF_HCATB);
  unsigned short* Wm2tB = (unsigned short*)(ws + OFF_WM2TB);
  unsigned short* midB  = (unsigned short*)(ws + OFF_MIDB);
  float* out   = (float*)d_out;

  k_setup<<<512, 256, 0, stream>>>(last_pos, lpr, dh, dc, W_emb, b_emb, lp, din, h_dec, cst);
  k_wc<<<2, 256, 0, stream>>>(W_sp, b_sp, W_pp1, b_pp1, Wc, bc);
  { dim3 gt(32, 16); k_tcvt<<<gt, 256, 0, stream>>>(W_pp2, Wp2t, 512, 1024); }
  { dim3 gt(32, 36); k_tcvt<<<gt, 256, 0, stream>>>(W_m1, Wm1t, 1152, 1024); }
  { dim3 gt(4, 32);  k_tcvt<<<gt, 256, 0, stream>>>(W_m2, Wm2tB, 1024, 128); }

  for (int t = 0; t < T_SEQ; t++) {
    k_step1<<<128, 512, 0, stream>>>(din, h_dec, cst, hcatB, lp, out,
                                     W_ih, b_ih, W_hh, b_hh, W_h2p, b_h2p,
                                     W_emb, b_emb, W_pp1 + 64*512, Wc, bc,
                                     PW, Aa, t);
    k_pool4<<<256, 512, 0, stream>>>(Aa, PW, Wp2t, b_pp2, hcatB);
    { dim3 gm(8, 16); k_m1h<<<gm, 512, 0, stream>>>(hcatB, Wm1t, b_m1, midB); }
    k_m2h<<<32, 256, 0, stream>>>(midB, Wm2tB, b_m2, h_dec);
  }
  k_hfin<<<512, 256, 0, stream>>>(h_dec, out);
}

// Round 6
// 1206.944 us; speedup vs baseline: 1.8673x; 1.8673x over previous
//
#include <hip/hip_runtime.h>
#include <math.h>

#define T_SEQ 12
// B=1024, NG=32, G=32, E=64, H=128, PP=512, BOT=1024, MLPD=1024

typedef __bf16 bf16x8 __attribute__((ext_vector_type(8)));
typedef float f32x4 __attribute__((ext_vector_type(4)));
typedef unsigned short u16x8 __attribute__((ext_vector_type(8)));

static __device__ __forceinline__ unsigned short bf16bits(float x) {
  return __builtin_bit_cast(unsigned short, (__bf16)x);
}

// Workspace layout (float offsets)
enum : int {
  OFF_LP    = 0,        // [1024,2]
  OFF_DIN   = 2048,     // [1024,64]
  OFF_C     = 198656,   // [1024,128]
  OFF_HDEC  = 329728,   // [1024,128]
  OFF_WC    = 460800,   // [2,512]
  OFF_BC    = 461824,   // [512]
  OFF_PW    = 462336,   // [1024,512]
  OFF_AA    = 986624,   // [1024,512]
  OFF_WP2T  = 1510912,  // [1024,512] bf16
  OFF_WM1T  = 1773056,  // [1024,1152] bf16
  OFF_HCATB = 2362880,  // [1024,1152] bf16 (h | pool)
  OFF_WM2TB = 2952704,  // [128,1024] bf16
  OFF_MIDB  = 3018240,  // [1024,1024] bf16
  OFF_WIHT  = 3542528,  // [64,512] f32 (W_ih^T)
  OFF_WHHT  = 3575296   // [128,512] f32 (W_hh^T)
};                      // end 3640832 floats = 14.6 MB

// XOR swizzle: permute 16B slots within each 128B group by row&7
#define SWZP(byte, row) ((byte) ^ (((row) & 7) << 4))

__global__ __launch_bounds__(256) void k_setup(
    const float* __restrict__ last_pos, const float* __restrict__ lpr,
    const float* __restrict__ dh, const float* __restrict__ dc,
    const float* __restrict__ W_emb, const float* __restrict__ b_emb,
    float* __restrict__ lp, float* __restrict__ din,
    float* __restrict__ h_dec, float* __restrict__ c) {
  int idx = blockIdx.x * 256 + threadIdx.x;  // 0..131071
  if (idx < 2048) lp[idx] = last_pos[idx];
  h_dec[idx] = dh[idx];
  c[idx] = dc[idx];
  if (idx < 65536) {
    int b = idx >> 6, e = idx & 63;
    din[idx] = lpr[b*2] * W_emb[e] + lpr[b*2+1] * W_emb[64+e] + b_emb[e];
  }
}

__global__ __launch_bounds__(256) void k_wc(
    const float* __restrict__ W_sp, const float* __restrict__ b_sp,
    const float* __restrict__ W_pp1, const float* __restrict__ b_pp1,
    float* __restrict__ Wc, float* __restrict__ bc) {
  int n = blockIdx.x * 256 + threadIdx.x;
  if (n >= 512) return;
  float a0 = 0.f, a1 = 0.f, ab = 0.f;
#pragma unroll 8
  for (int k = 0; k < 64; k++) {
    float w = W_pp1[k*512 + n];
    a0 += W_sp[k] * w;
    a1 += W_sp[64+k] * w;
    ab += b_sp[k] * w;
  }
  Wc[n] = a0; Wc[512+n] = a1; bc[n] = ab + b_pp1[n];
}

// Transpose + convert fp32 [R][C] -> bf16 [C][R]
__global__ __launch_bounds__(256) void k_tcvt(
    const float* __restrict__ src, unsigned short* __restrict__ dst,
    int R, int C) {
  __shared__ float t[32][33];
  const int bx = blockIdx.x * 32, by = blockIdx.y * 32;
  const int tx = threadIdx.x & 31, ty = threadIdx.x >> 5;
#pragma unroll
  for (int i = 0; i < 32; i += 8) t[ty+i][tx] = src[(size_t)(by+ty+i)*C + bx+tx];
  __syncthreads();
#pragma unroll
  for (int i = 0; i < 32; i += 8)
    dst[(size_t)(bx+ty+i)*R + by+tx] = bf16bits(t[tx][ty+i]);
}

// Transpose fp32 [R][C] -> fp32 [C][R]
__global__ __launch_bounds__(256) void k_t32(
    const float* __restrict__ src, float* __restrict__ dst, int R, int C) {
  __shared__ float t[32][33];
  const int bx = blockIdx.x * 32, by = blockIdx.y * 32;
  const int tx = threadIdx.x & 31, ty = threadIdx.x >> 5;
#pragma unroll
  for (int i = 0; i < 32; i += 8) t[ty+i][tx] = src[(size_t)(by+ty+i)*C + bx+tx];
  __syncthreads();
#pragma unroll
  for (int i = 0; i < 32; i += 8)
    dst[(size_t)(bx+ty+i)*R + by+tx] = t[tx][ty+i];
}

// Fused LSTM + h2pos + pool-A-prep: 4 batch rows/block, 512 threads, 256 blocks.
// Wiht/Whht are k-major (pre-transposed) -> fully coalesced weight reads.
__global__ __launch_bounds__(512) void k_step1(
    float* __restrict__ din, const float* __restrict__ h_dec,
    float* __restrict__ cst, unsigned short* __restrict__ hcatB,
    float* __restrict__ lp, float* __restrict__ pred,
    const float* __restrict__ Wiht, const float* __restrict__ b_ih,
    const float* __restrict__ Whht, const float* __restrict__ b_hh,
    const float* __restrict__ W_h2p, const float* __restrict__ b_h2p,
    const float* __restrict__ W_emb, const float* __restrict__ b_emb,
    const float* __restrict__ W1b, const float* __restrict__ Wc,
    const float* __restrict__ bc,
    float* __restrict__ PW, float* __restrict__ Aa, int t) {
  const int b0 = blockIdx.x * 4;
  const int tid = threadIdx.x;
  __shared__ float xh[4*192];
  __shared__ float gl[4*512];
  __shared__ float hbuf[4*128];
  __shared__ float relS[8], curS[8];

  for (int i = tid; i < 768; i += 512) {
    int r = i / 192, k = i - r*192;
    xh[i] = (k < 64) ? din[(b0+r)*64 + k] : h_dec[(b0+r)*128 + k - 64];
  }
  __syncthreads();
  {
    const int n = tid;
    float bias = b_ih[n] + b_hh[n];
    float acc[4] = {bias, bias, bias, bias};
#pragma unroll 8
    for (int k = 0; k < 64; k++) {
      float wv = Wiht[k*512 + n];
#pragma unroll
      for (int r = 0; r < 4; r++) acc[r] += xh[r*192 + k] * wv;
    }
#pragma unroll 8
    for (int k = 0; k < 128; k++) {
      float wv = Whht[k*512 + n];
#pragma unroll
      for (int r = 0; r < 4; r++) acc[r] += xh[r*192 + 64 + k] * wv;
    }
#pragma unroll
    for (int r = 0; r < 4; r++) gl[r*512 + n] = acc[r];
  }
  __syncthreads();
  {
    int r = tid >> 7, hh = tid & 127;
    float ig = gl[r*512 + hh],       fg = gl[r*512 + 128 + hh];
    float gg = gl[r*512 + 256 + hh], og = gl[r*512 + 384 + hh];
    ig = 1.f/(1.f+expf(-ig)); fg = 1.f/(1.f+expf(-fg));
    gg = tanhf(gg);           og = 1.f/(1.f+expf(-og));
    int row = b0 + r;
    float c2 = fg * cst[row*128 + hh] + ig * gg;
    float h2 = og * tanhf(c2);
    cst[row*128 + hh] = c2;
    hbuf[r*128 + hh] = h2;
    hcatB[(size_t)row*1152 + hh] = bf16bits(h2);
  }
  __syncthreads();
  if (tid < 128) {
    int r = tid >> 5, col = (tid >> 4) & 1, l16 = tid & 15;
    float s = 0.f;
    for (int k = l16; k < 128; k += 16) s += hbuf[r*128 + k] * W_h2p[k*2 + col];
#pragma unroll
    for (int off = 8; off > 0; off >>= 1) s += __shfl_xor(s, off);
    if (l16 == 0) {
      float rel = s + b_h2p[col];
      float old = lp[(b0+r)*2 + col];
      relS[r*2 + col] = rel;
      curS[r*2 + col] = old + rel;
      lp[(b0+r)*2 + col] = old + rel;
      pred[t*2048 + (b0+r)*2 + col] = rel;
    }
  }
  __syncthreads();
  if (tid < 256) {
    int r = tid >> 6, e = tid & 63;
    din[(b0+r)*64 + e] = relS[r*2]*W_emb[e] + relS[r*2+1]*W_emb[64+e] + b_emb[e];
  }
  {
    const int n = tid;
    float acc[4] = {0.f, 0.f, 0.f, 0.f};
#pragma unroll 4
    for (int k = 0; k < 128; k++) {
      float wv = W1b[k*512 + n];
#pragma unroll
      for (int r = 0; r < 4; r++) acc[r] += hbuf[r*128 + k] * wv;
    }
    float wc0 = Wc[n], wc1 = Wc[512+n], bcv = bc[n];
#pragma unroll
    for (int r = 0; r < 4; r++) {
      float pw = curS[r*2]*wc0 + curS[r*2+1]*wc1;
      PW[(size_t)(b0+r)*512 + n] = pw;
      Aa[(size_t)(b0+r)*512 + n] = acc[r] + pw + bcv;
    }
  }
}

// --- Pool GEMM: A-resident 128KB LDS + B through 16KB LDS chunk,
// reg-staged (T14): issue next-chunk loads -> MFMA -> barrier -> ds_write -> barrier.
// B chunk [256n][32k] bf16 (64B rows: inherently conflict-free b128 reads).
__global__ __launch_bounds__(512) void k_pool5(
    const float* __restrict__ Aa, const float* __restrict__ PW,
    const unsigned short* __restrict__ Wp2t, const float* __restrict__ bp2,
    unsigned short* __restrict__ hcatB) {
  const int bid = blockIdx.x;
  const int mt = (bid >> 3) & 7;
  const int g  = (bid & 7) + ((bid >> 6) << 3);
  const int tid = threadIdx.x, lane = tid & 63, w = tid >> 6;
  const int wr = w >> 2, wc = w & 3;     // 2m x 4n waves, wave tile 64m x 64n
  const int l15 = lane & 15, lhi = lane >> 4;
  __shared__ __align__(128) char lds[147456];
  char* As = lds;             // [128 rows][1024B] swizzled
  char* Bs = lds + 131072;    // [256 rows][64B] linear

  // Build A tile (rows m = ii*32 + j, i = mt*4+ii), conflict-free wave rows.
  {
    const int ke = lane * 8;
#pragma unroll 4
    for (int rr = 0; rr < 16; rr++) {
      const int r = rr * 8 + w;
      const int j = r & 31, ii = r >> 5;
      const float* aRow = Aa + (size_t)(g*32 + j)*512 + ke;
      const float* pRow = PW + (size_t)(g*32 + mt*4 + ii)*512 + ke;
      float4 a0 = *(const float4*)aRow;
      float4 a1 = *(const float4*)(aRow + 4);
      float4 p0 = *(const float4*)pRow;
      float4 p1 = *(const float4*)(pRow + 4);
      bf16x8 y;
      y[0] = (__bf16)fmaxf(a0.x - p0.x, 0.f);
      y[1] = (__bf16)fmaxf(a0.y - p0.y, 0.f);
      y[2] = (__bf16)fmaxf(a0.z - p0.z, 0.f);
      y[3] = (__bf16)fmaxf(a0.w - p0.w, 0.f);
      y[4] = (__bf16)fmaxf(a1.x - p1.x, 0.f);
      y[5] = (__bf16)fmaxf(a1.y - p1.y, 0.f);
      y[6] = (__bf16)fmaxf(a1.z - p1.z, 0.f);
      y[7] = (__bf16)fmaxf(a1.w - p1.w, 0.f);
      *(bf16x8*)(As + SWZP(r*1024 + lane*16, r)) = y;
    }
  }

  const int srow = tid >> 2;    // 0..127
  const int sslot = tid & 3;    // 16B slot within 64B row

  for (int nt = 0; nt < 4; nt++) {
    // prologue: stage chunk k0=0
    {
      u16x8 s0 = *(const u16x8*)(Wp2t + (size_t)(nt*256 + srow)*512 + sslot*8);
      u16x8 s1 = *(const u16x8*)(Wp2t + (size_t)(nt*256 + 128 + srow)*512 + sslot*8);
      *(u16x8*)(Bs + srow*64 + sslot*16) = s0;
      *(u16x8*)(Bs + (128 + srow)*64 + sslot*16) = s1;
    }
    __syncthreads();
    f32x4 acc[4][4] = {};
    for (int k0 = 0; k0 < 16; k0++) {
      u16x8 n0v, n1v;
      if (k0 < 15) {  // issue next-chunk loads early (hide under MFMA)
        n0v = *(const u16x8*)(Wp2t + (size_t)(nt*256 + srow)*512 + (k0+1)*32 + sslot*8);
        n1v = *(const u16x8*)(Wp2t + (size_t)(nt*256 + 128 + srow)*512 + (k0+1)*32 + sslot*8);
      }
      bf16x8 af[4];
#pragma unroll
      for (int mf = 0; mf < 4; mf++) {
        const int row = wr*64 + mf*16 + l15;
        af[mf] = *(const bf16x8*)(As + SWZP(row*1024 + k0*64 + lhi*16, row));
      }
      bf16x8 bfr[4];
#pragma unroll
      for (int nf = 0; nf < 4; nf++) {
        const int row = wc*64 + nf*16 + l15;
        bfr[nf] = *(const bf16x8*)(Bs + row*64 + lhi*16);
      }
#pragma unroll
      for (int mf = 0; mf < 4; mf++)
#pragma unroll
        for (int nf = 0; nf < 4; nf++)
          acc[mf][nf] = __builtin_amdgcn_mfma_f32_16x16x32_bf16(
              af[mf], bfr[nf], acc[mf][nf], 0, 0, 0);
      __syncthreads();
      if (k0 < 15) {
        *(u16x8*)(Bs + srow*64 + sslot*16) = n0v;
        *(u16x8*)(Bs + (128 + srow)*64 + sslot*16) = n1v;
        __syncthreads();
      }
    }
    // epilogue: max over j, bias, relu -> hcatB pool columns
#pragma unroll
    for (int isub = 0; isub < 2; isub++)
#pragma unroll
      for (int nf = 0; nf < 4; nf++) {
        f32x4 v0 = acc[isub*2][nf], v1 = acc[isub*2 + 1][nf];
        float mx = fmaxf(fmaxf(fmaxf(v0[0], v0[1]), fmaxf(v0[2], v0[3])),
                         fmaxf(fmaxf(v1[0], v1[1]), fmaxf(v1[2], v1[3])));
        mx = fmaxf(mx, __shfl_xor(mx, 16));
        mx = fmaxf(mx, __shfl_xor(mx, 32));
        if (lane < 16) {
          const int n = nt*256 + wc*64 + nf*16 + lane;
          const int i = mt*4 + wr*2 + isub;
          hcatB[(size_t)(g*32 + i)*1152 + 128 + n] =
              bf16bits(fmaxf(mx + bp2[n], 0.f));
        }
      }
  }
}

// mid = relu(hcatB @ Wm1t^T + b_m1) -> bf16 midB. LDS-staged (reg-stage T14),
// BM=64 BN=64, grid (16,16), 256 thr (4 waves 2x2), K=1152, 18 iters.
__global__ __launch_bounds__(256) void k_m1s(
    const unsigned short* __restrict__ A, const unsigned short* __restrict__ Bw,
    const float* __restrict__ bias, unsigned short* __restrict__ outB) {
  const int nt = blockIdx.x, mt = blockIdx.y;
  const int tid = threadIdx.x, lane = tid & 63, w = tid >> 6;
  const int wr = w >> 1, wc = w & 1;
  const int l15 = lane & 15, lhi = lane >> 4;
  __shared__ __align__(128) char lds[16384];  // A [64][128B] @0, B @8192

  const int srow = tid >> 3, sslot = tid & 7;
  const unsigned short* aSrc = A  + (size_t)(mt*64)*1152;
  const unsigned short* bSrc = Bw + (size_t)(nt*64)*1152;

  u16x8 cur0, cur1, cur2, cur3;
  cur0 = *(const u16x8*)(aSrc + (size_t)srow*1152      + sslot*8);
  cur1 = *(const u16x8*)(aSrc + (size_t)(32+srow)*1152 + sslot*8);
  cur2 = *(const u16x8*)(bSrc + (size_t)srow*1152      + sslot*8);
  cur3 = *(const u16x8*)(bSrc + (size_t)(32+srow)*1152 + sslot*8);
  *(u16x8*)(lds + SWZP(srow*128 + sslot*16, srow)) = cur0;
  *(u16x8*)(lds + SWZP((32+srow)*128 + sslot*16, 32+srow)) = cur1;
  *(u16x8*)(lds + 8192 + SWZP(srow*128 + sslot*16, srow)) = cur2;
  *(u16x8*)(lds + 8192 + SWZP((32+srow)*128 + sslot*16, 32+srow)) = cur3;
  __syncthreads();

  f32x4 acc[2][2] = {};
  for (int c = 0; c < 18; c++) {
    u16x8 nx0, nx1, nx2, nx3;
    if (c < 17) {
      const int kb = (c+1)*64 + sslot*8;
      nx0 = *(const u16x8*)(aSrc + (size_t)srow*1152      + kb);
      nx1 = *(const u16x8*)(aSrc + (size_t)(32+srow)*1152 + kb);
      nx2 = *(const u16x8*)(bSrc + (size_t)srow*1152      + kb);
      nx3 = *(const u16x8*)(bSrc + (size_t)(32+srow)*1152 + kb);
    }
    bf16x8 af[2][2], bf_[2][2];
#pragma unroll
    for (int ks = 0; ks < 2; ks++) {
#pragma unroll
      for (int mf = 0; mf < 2; mf++) {
        const int row = wr*32 + mf*16 + l15;
        af[mf][ks] = *(const bf16x8*)(lds + SWZP(row*128 + ks*64 + lhi*16, row));
      }
#pragma unroll
      for (int nf = 0; nf < 2; nf++) {
        const int row = wc*32 + nf*16 + l15;
        bf_[nf][ks] = *(const bf16x8*)(lds + 8192 + SWZP(row*128 + ks*64 + lhi*16, row));
      }
    }
#pragma unroll
    for (int ks = 0; ks < 2; ks++)
#pragma unroll
      for (int mf = 0; mf < 2; mf++)
#pragma unroll
        for (int nf = 0; nf < 2; nf++)
          acc[mf][nf] = __builtin_amdgcn_mfma_f32_16x16x32_bf16(
              af[mf][ks], bf_[nf][ks], acc[mf][nf], 0, 0, 0);
    __syncthreads();
    if (c < 17) {
      *(u16x8*)(lds + SWZP(srow*128 + sslot*16, srow)) = nx0;
      *(u16x8*)(lds + SWZP((32+srow)*128 + sslot*16, 32+srow)) = nx1;
      *(u16x8*)(lds + 8192 + SWZP(srow*128 + sslot*16, srow)) = nx2;
      *(u16x8*)(lds + 8192 + SWZP((32+srow)*128 + sslot*16, 32+srow)) = nx3;
      __syncthreads();
    }
  }
#pragma unroll
  for (int mf = 0; mf < 2; mf++)
#pragma unroll
    for (int nf = 0; nf < 2; nf++) {
      const int col = nt*64 + wc*32 + nf*16 + l15;
      const float bv = bias[col];
#pragma unroll
      for (int r = 0; r < 4; r++) {
        const int row = mt*64 + wr*32 + mf*16 + lhi*4 + r;
        outB[(size_t)row*1024 + col] = bf16bits(fmaxf(acc[mf][nf][r] + bv, 0.f));
      }
    }
}

// h_dec = relu(midB @ Wm2tB^T + b_m2) fp32. Same structure, K=1024, grid (2,16).
__global__ __launch_bounds__(256) void k_m2s(
    const unsigned short* __restrict__ A, const unsigned short* __restrict__ Bw,
    const float* __restrict__ bias, float* __restrict__ hd) {
  const int nt = blockIdx.x, mt = blockIdx.y;
  const int tid = threadIdx.x, lane = tid & 63, w = tid >> 6;
  const int wr = w >> 1, wc = w & 1;
  const int l15 = lane & 15, lhi = lane >> 4;
  __shared__ __align__(128) char lds[16384];

  const int srow = tid >> 3, sslot = tid & 7;
  const unsigned short* aSrc = A  + (size_t)(mt*64)*1024;
  const unsigned short* bSrc = Bw + (size_t)(nt*64)*1024;

  u16x8 cur0, cur1, cur2, cur3;
  cur0 = *(const u16x8*)(aSrc + (size_t)srow*1024      + sslot*8);
  cur1 = *(const u16x8*)(aSrc + (size_t)(32+srow)*1024 + sslot*8);
  cur2 = *(const u16x8*)(bSrc + (size_t)srow*1024      + sslot*8);
  cur3 = *(const u16x8*)(bSrc + (size_t)(32+srow)*1024 + sslot*8);
  *(u16x8*)(lds + SWZP(srow*128 + sslot*16, srow)) = cur0;
  *(u16x8*)(lds + SWZP((32+srow)*128 + sslot*16, 32+srow)) = cur1;
  *(u16x8*)(lds + 8192 + SWZP(srow*128 + sslot*16, srow)) = cur2;
  *(u16x8*)(lds + 8192 + SWZP((32+srow)*128 + sslot*16, 32+srow)) = cur3;
  __syncthreads();

  f32x4 acc[2][2] = {};
  for (int c = 0; c < 16; c++) {
    u16x8 nx0, nx1, nx2, nx3;
    if (c < 15) {
      const int kb = (c+1)*64 + sslot*8;
      nx0 = *(const u16x8*)(aSrc + (size_t)srow*1024      + kb);
      nx1 = *(const u16x8*)(aSrc + (size_t)(32+srow)*1024 + kb);
      nx2 = *(const u16x8*)(bSrc + (size_t)srow*1024      + kb);
      nx3 = *(const u16x8*)(bSrc + (size_t)(32+srow)*1024 + kb);
    }
    bf16x8 af[2][2], bf_[2][2];
#pragma unroll
    for (int ks = 0; ks < 2; ks++) {
#pragma unroll
      for (int mf = 0; mf < 2; mf++) {
        const int row = wr*32 + mf*16 + l15;
        af[mf][ks] = *(const bf16x8*)(lds + SWZP(row*128 + ks*64 + lhi*16, row));
      }
#pragma unroll
      for (int nf = 0; nf < 2; nf++) {
        const int row = wc*32 + nf*16 + l15;
        bf_[nf][ks] = *(const bf16x8*)(lds + 8192 + SWZP(row*128 + ks*64 + lhi*16, row));
      }
    }
#pragma unroll
    for (int ks = 0; ks < 2; ks++)
#pragma unroll
      for (int mf = 0; mf < 2; mf++)
#pragma unroll
        for (int nf = 0; nf < 2; nf++)
          acc[mf][nf] = __builtin_amdgcn_mfma_f32_16x16x32_bf16(
              af[mf][ks], bf_[nf][ks], acc[mf][nf], 0, 0, 0);
    __syncthreads();
    if (c < 15) {
      *(u16x8*)(lds + SWZP(srow*128 + sslot*16, srow)) = nx0;
      *(u16x8*)(lds + SWZP((32+srow)*128 + sslot*16, 32+srow)) = nx1;
      *(u16x8*)(lds + 8192 + SWZP(srow*128 + sslot*16, srow)) = nx2;
      *(u16x8*)(lds + 8192 + SWZP((32+srow)*128 + sslot*16, 32+srow)) = nx3;
      __syncthreads();
    }
  }
#pragma unroll
  for (int mf = 0; mf < 2; mf++)
#pragma unroll
    for (int nf = 0; nf < 2; nf++) {
      const int col = nt*64 + wc*32 + nf*16 + l15;
      const float bv = bias[col];
#pragma unroll
      for (int r = 0; r < 4; r++) {
        const int row = mt*64 + wr*32 + mf*16 + lhi*4 + r;
        hd[(size_t)row*128 + col] = fmaxf(acc[mf][nf][r] + bv, 0.f);
      }
    }
}

__global__ __launch_bounds__(256) void k_hfin(const float* __restrict__ h_dec,
                                              float* __restrict__ out) {
  int idx = blockIdx.x * 256 + threadIdx.x;
  if (idx < 131072) out[24576 + idx] = h_dec[idx];
}

extern "C" void kernel_launch(void* const* d_in, const int* in_sizes, int n_in,
                              void* d_out, int out_size, void* d_ws, size_t ws_size,
                              hipStream_t stream) {
  const float* last_pos = (const float*)d_in[0];
  const float* lpr      = (const float*)d_in[1];
  const float* dh       = (const float*)d_in[2];
  const float* dc       = (const float*)d_in[3];
  const float* W_emb = (const float*)d_in[5];
  const float* b_emb = (const float*)d_in[6];
  const float* W_ih  = (const float*)d_in[7];
  const float* b_ih  = (const float*)d_in[8];
  const float* W_hh  = (const float*)d_in[9];
  const float* b_hh  = (const float*)d_in[10];
  const float* W_h2p = (const float*)d_in[11];
  const float* b_h2p = (const float*)d_in[12];
  const float* W_sp  = (const float*)d_in[13];
  const float* b_sp  = (const float*)d_in[14];
  const float* W_pp1 = (const float*)d_in[15];
  const float* b_pp1 = (const float*)d_in[16];
  const float* W_pp2 = (const float*)d_in[17];
  const float* b_pp2 = (const float*)d_in[18];
  const float* W_m1  = (const float*)d_in[19];
  const float* b_m1  = (const float*)d_in[20];
  const float* W_m2  = (const float*)d_in[21];
  const float* b_m2  = (const float*)d_in[22];

  float* ws    = (float*)d_ws;
  float* lp    = ws + OFF_LP;
  float* din   = ws + OFF_DIN;
  float* cst   = ws + OFF_C;
  float* h_dec = ws + OFF_HDEC;
  float* Wc    = ws + OFF_WC;
  float* bc    = ws + OFF_BC;
  float* PW    = ws + OFF_PW;
  float* Aa    = ws + OFF_AA;
  unsigned short* Wp2t  = (unsigned short*)(ws + OFF_WP2T);
  unsigned short* Wm1t  = (unsigned short*)(ws + OFF_WM1T);
  unsigned short* hcatB = (unsigned short*)(ws + OFF_HCATB);
  unsigned short* Wm2tB = (unsigned short*)(ws + OFF_WM2TB);
  unsigned short* midB  = (unsigned short*)(ws + OFF_MIDB);
  float* Wiht  = ws + OFF_WIHT;
  float* Whht  = ws + OFF_WHHT;
  float* out   = (float*)d_out;

  k_setup<<<512, 256, 0, stream>>>(last_pos, lpr, dh, dc, W_emb, b_emb, lp, din, h_dec, cst);
  k_wc<<<2, 256, 0, stream>>>(W_sp, b_sp, W_pp1, b_pp1, Wc, bc);
  { dim3 gt(32, 16); k_tcvt<<<gt, 256, 0, stream>>>(W_pp2, Wp2t, 512, 1024); }
  { dim3 gt(32, 36); k_tcvt<<<gt, 256, 0, stream>>>(W_m1, Wm1t, 1152, 1024); }
  { dim3 gt(4, 32);  k_tcvt<<<gt, 256, 0, stream>>>(W_m2, Wm2tB, 1024, 128); }
  { dim3 gt(2, 16);  k_t32<<<gt, 256, 0, stream>>>(W_ih, Wiht, 512, 64); }
  { dim3 gt(4, 16);  k_t32<<<gt, 256, 0, stream>>>(W_hh, Whht, 512, 128); }

  for (int t = 0; t < T_SEQ; t++) {
    k_step1<<<256, 512, 0, stream>>>(din, h_dec, cst, hcatB, lp, out,
                                     Wiht, b_ih, Whht, b_hh, W_h2p, b_h2p,
                                     W_emb, b_emb, W_pp1 + 64*512, Wc, bc,
                                     PW, Aa, t);
    k_pool5<<<256, 512, 0, stream>>>(Aa, PW, Wp2t, b_pp2, hcatB);
    { dim3 gm(16, 16); k_m1s<<<gm, 256, 0, stream>>>(hcatB, Wm1t, b_m1, midB); }
    { dim3 gm(2, 16);  k_m2s<<<gm, 256, 0, stream>>>(midB, Wm2tB, b_m2, h_dec); }
  }
  k_hfin<<<512, 256, 0, stream>>>(h_dec, out);
}